// Round 12
// baseline (435.368 us; speedup 1.0000x reference)
//
#include <hip/hip_runtime.h>

#define N_NODES 50000
#define N_EDGES 600000
#define D_IN 128
#define D_MID 128
#define D_ATTR 32
#define D_OUT 128
#define D_EMB 256
#define D_H 768
#define K_TOP 16
#define D_CAT (D_OUT + D_ATTR)   // 160
#define N_CHUNKBLKS 196          // ceil(50000/256)
#define N_CAND (N_CHUNKBLKS * K_TOP)   // 3136
#define CSLOTS 13                // ceil(3136/256)
#define WSCALE 262144.0f         // 2^18 fixed-point for packed degree
#define CS_BLOCKS 768            // 768 = 3*256 exactly (reduce reads 3/thread)

// ---------------------------------------------------------------- init
__global__ void k_init(unsigned long long* packed, float* q) {
    int i = blockIdx.x * blockDim.x + threadIdx.x;
    if (i < N_NODES) packed[i] = 0ULL;
    if (i < D_CAT)   q[i] = 0.0f;
}

// ---------------------------------------------------------------- packed degree+count (+rank)
// atomic returns OLD value: old>>40 = this edge's unique rank within its dst row.
__global__ void k_deg(const int* __restrict__ dst, const float* __restrict__ w,
                      unsigned long long* __restrict__ packed, int* __restrict__ rank) {
    int e = blockIdx.x * blockDim.x + threadIdx.x;
    if (e < N_EDGES) {
        int d = dst[e];
        unsigned long long qv = (1ULL << 40)
                              + (unsigned long long)__float2uint_rn(w[e] * WSCALE);
        unsigned long long old = atomicAdd(&packed[d], qv);
        rank[e] = (int)(old >> 40);
    }
}

// ---------------------------------------------------------------- scan stage 1 (+ fused dinv)
__global__ __launch_bounds__(256) void k_scan_blk(const unsigned long long* __restrict__ packed,
                                                  float* __restrict__ dinv,
                                                  int* __restrict__ incl,
                                                  int* __restrict__ bsum) {
    __shared__ int sm[256];
    int tid = threadIdx.x;
    int i = blockIdx.x * 256 + tid;
    unsigned long long p = (i < N_NODES) ? packed[i] : 0ULL;
    int v = (int)(p >> 40);
    if (i < N_NODES) {
        float wsum = (float)(p & 0xFFFFFFFFFFULL) * (1.0f / WSCALE);
        dinv[i] = rsqrtf(1.0f + wsum);   // self-loop contributes 1
    }
    sm[tid] = v;
    __syncthreads();
    for (int off = 1; off < 256; off <<= 1) {
        int t = (tid >= off) ? sm[tid - off] : 0;
        __syncthreads();
        sm[tid] += t;
        __syncthreads();
    }
    if (i < N_NODES) incl[i] = sm[tid];
    if (tid == 255) bsum[blockIdx.x] = sm[255];
}

__global__ __launch_bounds__(256) void k_scan_top(const int* __restrict__ bsum,
                                                  int* __restrict__ boff) {
    __shared__ int sm[256];
    int tid = threadIdx.x;
    int v = (tid < N_CHUNKBLKS) ? bsum[tid] : 0;
    sm[tid] = v;
    __syncthreads();
    for (int off = 1; off < 256; off <<= 1) {
        int t = (tid >= off) ? sm[tid - off] : 0;
        __syncthreads();
        sm[tid] += t;
        __syncthreads();
    }
    if (tid < N_CHUNKBLKS) boff[tid] = sm[tid] - v;   // exclusive
}

__global__ __launch_bounds__(256) void k_scan_add(const int* __restrict__ incl,
                                                  const int* __restrict__ boff,
                                                  int* __restrict__ row_ptr) {
    int i = blockIdx.x * 256 + threadIdx.x;
    if (i < N_NODES) {
        row_ptr[i + 1] = incl[i] + boff[blockIdx.x];
        if (i == 0) row_ptr[0] = 0;
    }
}

// ---------------------------------------------------------------- CSR fill (no cursor atomic)
__global__ void k_fill(const int* __restrict__ src, const int* __restrict__ dst,
                       const float* __restrict__ w, const int* __restrict__ rank,
                       const float* __restrict__ dinv, const int* __restrict__ rowp,
                       int2* __restrict__ recs) {
    int e = blockIdx.x * blockDim.x + threadIdx.x;
    if (e < N_EDGES) {
        int s = src[e], d = dst[e];
        int pos = rowp[d] + rank[e];
        float nr = dinv[s] * w[e] * dinv[d];
        recs[pos] = make_int2(s, __float_as_int(nr));
    }
}

// ---------------------------------------------------------------- GEMM: out[N,128] = [in1|in2] @ W
// GBM=64 rows/block, 256 thr, 2 rows x 16 strided cols/thread. Conflict-free ws reads.
#define GBM 64
#define GBK 32
__global__ __launch_bounds__(256) void k_gemm(
    const float* __restrict__ in1, int d1,
    const float* __restrict__ in2, int d2,
    const float* __restrict__ W,      // [(d1+d2) x 128]
    float* __restrict__ out)          // [N x 128]
{
    __shared__ float xs[GBM][GBK + 1];   // 64x33
    __shared__ float ws[GBK][128];       // 32x128
    int tid = threadIdx.x;
    int cx = tid & 7;          // strided col groups: cx*4 + j4*32
    int ry = tid >> 3;         // rows ry*2, ry*2+1
    int row0 = blockIdx.x * GBM;
    float acc[2][16];
#pragma unroll
    for (int i = 0; i < 2; ++i)
#pragma unroll
        for (int j = 0; j < 16; ++j) acc[i][j] = 0.0f;
    int KD = d1 + d2;
    for (int kt = 0; kt < KD; kt += GBK) {
        const float* srcp; int sd, scol;
        if (kt < d1) { srcp = in1; sd = d1; scol = kt; }
        else         { srcp = in2; sd = d2; scol = kt - d1; }
#pragma unroll
        for (int i = 0; i < 2; ++i) {
            int vid = tid + i * 256;
            int rr = vid >> 3;
            int kc = (vid & 7) * 4;
            int r = row0 + rr;
            float4 val = make_float4(0.f, 0.f, 0.f, 0.f);
            if (r < N_NODES)
                val = *(const float4*)(srcp + (size_t)r * sd + scol + kc);
            xs[rr][kc + 0] = val.x;
            xs[rr][kc + 1] = val.y;
            xs[rr][kc + 2] = val.z;
            xs[rr][kc + 3] = val.w;
        }
#pragma unroll
        for (int i = 0; i < 4; ++i) {
            int vid = tid + i * 256;
            int kk = vid >> 5;
            int c = (vid & 31) * 4;
            *(float4*)&ws[kk][c] = *(const float4*)(W + (size_t)(kt + kk) * 128 + c);
        }
        __syncthreads();
#pragma unroll
        for (int kk = 0; kk < GBK; ++kk) {
            float xv0 = xs[ry * 2 + 0][kk];
            float xv1 = xs[ry * 2 + 1][kk];
            float wv[16];
#pragma unroll
            for (int j4 = 0; j4 < 4; ++j4)
                *(float4*)&wv[j4 * 4] = *(float4*)&ws[kk][cx * 4 + j4 * 32];
#pragma unroll
            for (int j = 0; j < 16; ++j) {
                acc[0][j] += xv0 * wv[j];
                acc[1][j] += xv1 * wv[j];
            }
        }
        __syncthreads();
    }
#pragma unroll
    for (int i = 0; i < 2; ++i) {
        int r = row0 + ry * 2 + i;
        if (r < N_NODES) {
#pragma unroll
            for (int j4 = 0; j4 < 4; ++j4)
                *(float4*)(out + (size_t)r * 128 + cx * 4 + j4 * 32)
                    = *(float4*)&acc[i][j4 * 4];
        }
    }
}

// ---------------------------------------------------------------- column-sliced aggregation
// slice = blockIdx&7 -> XCD affinity (round-robin dispatch heuristic; perf-only).
// Each XCD gathers only its 16-col slice of t (3.2 MB, L2-resident).
// One wave per node: 64 lanes = 4 edge-slots (j4) x 16 cols. Zero-weight padding
// beyond the row length kills all guards; self/bias added AFTER the j4-reduce.
__global__ __launch_bounds__(256) void k_agg(
    const float* __restrict__ t, const float* __restrict__ dinv,
    const int* __restrict__ rowp, const int2* __restrict__ recs,
    const float* __restrict__ bias,
    float* __restrict__ out, int relu_flag)
{
    int slice = blockIdx.x & 7;
    int ng    = blockIdx.x >> 3;
    int wav   = threadIdx.x >> 6;
    int lane  = threadIdx.x & 63;
    int node  = ng * 4 + wav;            // 12500*4 = 50000 exact
    int j4   = lane >> 4;                // edge sub-slot 0..3
    int col  = slice * 16 + (lane & 15);
    float acc = 0.0f;
    int e0 = rowp[node], e1 = rowp[node + 1];
    int len = e1 - e0;
    for (int base = 0; base < len; base += 64) {
        int m = len - base; if (m > 64) m = 64;
        int2 myrec = make_int2(0, 0);    // w=0 padding: lanes >= m contribute nothing
        if (lane < m) {
            long long rl = __builtin_nontemporal_load(
                (const long long*)&recs[e0 + base + lane]);
            myrec.x = (int)(rl & 0xffffffffLL);
            myrec.y = (int)(rl >> 32);
        }
        for (int jb = 0; jb < m; jb += 16) {
            int ja = jb + j4, jb1 = jb + 4 + j4, jc = jb + 8 + j4, jd = jb + 12 + j4;
            int   s0 = __shfl(myrec.x, ja, 64);
            int   s1 = __shfl(myrec.x, jb1, 64);
            int   s2 = __shfl(myrec.x, jc, 64);
            int   s3 = __shfl(myrec.x, jd, 64);
            float w0 = __int_as_float(__shfl(myrec.y, ja, 64));
            float w1 = __int_as_float(__shfl(myrec.y, jb1, 64));
            float w2 = __int_as_float(__shfl(myrec.y, jc, 64));
            float w3 = __int_as_float(__shfl(myrec.y, jd, 64));
            float u0 = t[(size_t)s0 * 128 + col];
            float u1 = t[(size_t)s1 * 128 + col];
            float u2 = t[(size_t)s2 * 128 + col];
            float u3 = t[(size_t)s3 * 128 + col];
            acc += w0 * u0 + w1 * u1 + w2 * u2 + w3 * u3;
        }
    }
    // reduce the 4 edge-slot partials (lanes differing by 16/32)
    acc += __shfl_xor(acc, 16, 64);
    acc += __shfl_xor(acc, 32, 64);
    float di = dinv[node];
    acc += di * di * t[(size_t)node * 128 + col];
    acc += bias[col];
    if (relu_flag) acc = fmaxf(acc, 0.0f);
    if (j4 == 0) out[(size_t)node * 128 + col] = acc;
}

// ---------------------------------------------------------------- q = hidden_state @ Wattn  [160]
__global__ void k_q(const float* __restrict__ hs, const float* __restrict__ Wattn,
                    float* __restrict__ q) {
    int j = threadIdx.x;
    if (j >= D_CAT) return;
    int k0 = blockIdx.x * (D_H / 8);       // grid 8
    float acc = 0.0f;
    for (int k = k0; k < k0 + D_H / 8; k++) acc += hs[k] * Wattn[k * D_CAT + j];
    atomicAdd(&q[j], acc);
}

// ---------------------------------------------------------------- post: colsum partials + scores
// One streaming pass over h2+attr. Phase1: 32-lane groups own a row -> colsum float4
// accum + score dot (width-32 shfl reduce, stashed in LDS). Phase2: attr, width-8.
__global__ __launch_bounds__(256) void k_post(const float* __restrict__ h2,
                                              const float* __restrict__ attr,
                                              const float* __restrict__ q,
                                              float* __restrict__ partial,
                                              float* __restrict__ scores) {
    __shared__ float4 sm[256];
    __shared__ float rowsc[80];
    int tid = threadIdx.x;
    int per = (N_NODES + CS_BLOCKS - 1) / CS_BLOCKS;   // 66
    int r0 = blockIdx.x * per;
    int r1 = min(N_NODES, r0 + per);
    float* myrow = partial + (size_t)blockIdx.x * D_CAT;
    {
        const float4* h4 = (const float4*)h2;          // row stride 32 float4
        int c = tid & 31;
        float4 qv = ((const float4*)q)[c];
        float4 acc = make_float4(0.f, 0.f, 0.f, 0.f);
        for (int r = r0 + (tid >> 5); r < r1; r += 8) {
            float4 v = h4[(size_t)r * 32 + c];
            acc.x += v.x; acc.y += v.y; acc.z += v.z; acc.w += v.w;
            float sd = v.x * qv.x + v.y * qv.y + v.z * qv.z + v.w * qv.w;
#pragma unroll
            for (int off = 16; off; off >>= 1) sd += __shfl_xor(sd, off, 32);
            if (c == 0) rowsc[r - r0] = sd;
        }
        sm[tid] = acc;
        __syncthreads();
        if (tid < 32) {
            float4 s = sm[tid];
#pragma unroll
            for (int g = 1; g < 8; ++g) {
                float4 v = sm[g * 32 + tid];
                s.x += v.x; s.y += v.y; s.z += v.z; s.w += v.w;
            }
            ((float4*)myrow)[tid] = s;
        }
        __syncthreads();
    }
    {
        const float4* a4 = (const float4*)attr;        // row stride 8 float4
        int c = tid & 7;
        float4 qv = ((const float4*)q)[32 + c];
        float4 acc = make_float4(0.f, 0.f, 0.f, 0.f);
        for (int r = r0 + (tid >> 3); r < r1; r += 32) {
            float4 v = a4[(size_t)r * 8 + c];
            acc.x += v.x; acc.y += v.y; acc.z += v.z; acc.w += v.w;
            float sd = v.x * qv.x + v.y * qv.y + v.z * qv.z + v.w * qv.w;
#pragma unroll
            for (int off = 4; off; off >>= 1) sd += __shfl_xor(sd, off, 8);
            if (c == 0) scores[r] = rowsc[r - r0] + sd;
        }
        sm[tid] = acc;
        __syncthreads();
        if (tid < 8) {
            float4 s = sm[tid];
#pragma unroll
            for (int g = 1; g < 32; ++g) {
                float4 v = sm[g * 8 + tid];
                s.x += v.x; s.y += v.y; s.z += v.z; s.w += v.w;
            }
            ((float4*)(myrow + D_OUT))[tid] = s;
        }
    }
}

// ---------------------------------------------------------------- column sums, stage B
__global__ __launch_bounds__(256) void k_colsum_reduce(const float* __restrict__ partial,
                                                       float* __restrict__ colsum) {
    __shared__ float4 sm[256];
    int tid = threadIdx.x;
    int cg = blockIdx.x;
    float4 acc = make_float4(0.f, 0.f, 0.f, 0.f);
#pragma unroll
    for (int k = 0; k < 3; ++k) {
        int b = tid + k * 256;
        float4 v = *(const float4*)(partial + (size_t)b * D_CAT + cg * 4);
        acc.x += v.x; acc.y += v.y; acc.z += v.z; acc.w += v.w;
    }
    sm[tid] = acc;
    __syncthreads();
    for (int off = 128; off; off >>= 1) {
        if (tid < off) {
            float4 v = sm[tid + off];
            sm[tid].x += v.x; sm[tid].y += v.y; sm[tid].z += v.z; sm[tid].w += v.w;
        }
        __syncthreads();
    }
    if (tid == 0) *(float4*)(colsum + cg * 4) = sm[0];
}

// ---------------------------------------------------------------- top-k stage 1 (wave-shuffle)
__global__ __launch_bounds__(256) void k_top1(const float* __restrict__ scores,
                                              float* __restrict__ cand_s,
                                              int* __restrict__ cand_i) {
    int tid = threadIdx.x;
    int lane = tid & 63;
    int wave = tid >> 6;
    int i = blockIdx.x * 256 + tid;
    float s = (i < N_NODES) ? scores[i] : -INFINITY;
    int ix = i;
    __shared__ float wls[4];
    __shared__ int   wli[4];
    __shared__ int   fin_i;
    for (int it = 0; it < K_TOP; ++it) {
        float bs = s; int bi = ix;
#pragma unroll
        for (int off = 32; off; off >>= 1) {
            float s2 = __shfl_xor(bs, off, 64);
            int   i2 = __shfl_xor(bi, off, 64);
            if (s2 > bs || (s2 == bs && i2 < bi)) { bs = s2; bi = i2; }
        }
        if (lane == 0) { wls[wave] = bs; wli[wave] = bi; }
        __syncthreads();
        if (tid == 0) {
            float f = wls[0]; int fi = wli[0];
#pragma unroll
            for (int w = 1; w < 4; ++w)
                if (wls[w] > f || (wls[w] == f && wli[w] < fi)) { f = wls[w]; fi = wli[w]; }
            cand_s[blockIdx.x * K_TOP + it] = f;
            cand_i[blockIdx.x * K_TOP + it] = fi;
            fin_i = fi;
        }
        __syncthreads();
        if (ix == fin_i) s = -INFINITY;
    }
}

// ---------------------------------------------------------------- top-k stage 2 + emb + gather
__global__ __launch_bounds__(256) void k_top2emb(
    const float* __restrict__ cand_s, const int* __restrict__ cand_i,
    const float* __restrict__ colsum, const float* __restrict__ Wmap,
    const float* __restrict__ bmap,
    const float* __restrict__ h2, const float* __restrict__ attr,
    float* __restrict__ out)
{
    float s[CSLOTS]; int ix[CSLOTS];
    int tid = threadIdx.x;
    int lane = tid & 63;
    int wave = tid >> 6;
#pragma unroll
    for (int j = 0; j < CSLOTS; ++j) {
        int c = tid + j * 256;
        s[j]  = (c < N_CAND) ? cand_s[c] : -INFINITY;
        ix[j] = (c < N_CAND) ? cand_i[c] : 0x7fffffff;
    }
    __shared__ float wsum_s[4];
    __shared__ int   wsum_i[4];
    __shared__ int   win_i;
    __shared__ int   ti[K_TOP];
    for (int it = 0; it < K_TOP; ++it) {
        float bs = -INFINITY; int bi = 0x7fffffff;
#pragma unroll
        for (int j = 0; j < CSLOTS; ++j) {
            if (s[j] > bs || (s[j] == bs && ix[j] < bi)) { bs = s[j]; bi = ix[j]; }
        }
#pragma unroll
        for (int off = 32; off; off >>= 1) {
            float s2 = __shfl_xor(bs, off, 64);
            int   i2 = __shfl_xor(bi, off, 64);
            if (s2 > bs || (s2 == bs && i2 < bi)) { bs = s2; bi = i2; }
        }
        if (lane == 0) { wsum_s[wave] = bs; wsum_i[wave] = bi; }
        __syncthreads();
        if (tid == 0) {
            float ws0 = wsum_s[0]; int wi0 = wsum_i[0];
#pragma unroll
            for (int w = 1; w < 4; ++w) {
                float s2 = wsum_s[w]; int i2 = wsum_i[w];
                if (s2 > ws0 || (s2 == ws0 && i2 < wi0)) { ws0 = s2; wi0 = i2; }
            }
            win_i = wi0;
            ti[it] = wi0;
        }
        __syncthreads();
        int w = win_i;
#pragma unroll
        for (int j = 0; j < CSLOTS; ++j)
            if (ix[j] == w) s[j] = -INFINITY;
        __syncthreads();
    }
    __shared__ float cs[D_CAT];
    if (tid < D_CAT) cs[tid] = colsum[tid];
    __syncthreads();
    float acc = 0.0f;
#pragma unroll 8
    for (int k = 0; k < D_CAT; ++k) acc += cs[k] * Wmap[k * D_EMB + tid];
    out[tid] = acc * (1.0f / N_NODES) + bmap[tid];
    for (int idx = tid; idx < K_TOP * D_CAT; idx += 256) {
        int kk = idx / D_CAT;
        int d = idx % D_CAT;
        int node = ti[kk];
        out[D_EMB + idx] = (d < D_OUT) ? h2[node * D_OUT + d]
                                       : attr[node * D_ATTR + (d - D_OUT)];
    }
}

// ================================================================ host
extern "C" void kernel_launch(void* const* d_in, const int* in_sizes, int n_in,
                              void* d_out, int out_size, void* d_ws, size_t ws_size,
                              hipStream_t stream) {
    const float* x      = (const float*)d_in[0];
    const float* attr   = (const float*)d_in[1];
    const float* ew     = (const float*)d_in[2];
    const float* hs     = (const float*)d_in[3];
    const int*   ei     = (const int*)d_in[4];
    const float* W1     = (const float*)d_in[5];
    const float* b1     = (const float*)d_in[6];
    const float* W2     = (const float*)d_in[7];
    const float* b2     = (const float*)d_in[8];
    const float* Wmap   = (const float*)d_in[9];
    const float* bmap   = (const float*)d_in[10];
    const float* Wattn  = (const float*)d_in[11];
    float* out = (float*)d_out;
    const int* e_src = ei;
    const int* e_dst = ei + N_EDGES;

    size_t off = 0;
    auto alloc = [&](size_t bytes) {
        void* p = (char*)d_ws + off;
        off += (bytes + 255) / 256 * 256;
        return p;
    };
    unsigned long long* packed = (unsigned long long*)alloc((size_t)N_NODES * 8);
    float* dinv   = (float*)alloc((size_t)N_NODES * 4);
    int*   rowp   = (int*)  alloc((size_t)(N_NODES + 1) * 4);
    int*   rank   = (int*)  alloc((size_t)N_EDGES * 4);
    int2*  recs   = (int2*) alloc((size_t)N_EDGES * 8);
    float* bufA   = (float*)alloc((size_t)N_NODES * 128 * 4);
    float* bufB   = (float*)alloc((size_t)N_NODES * 128 * 4);
    float* scores = (float*)alloc((size_t)N_NODES * 4);
    float* q      = (float*)alloc(D_CAT * 4);
    float* colsum = (float*)alloc(D_CAT * 4);
    float* partial= (float*)alloc((size_t)CS_BLOCKS * D_CAT * 4);
    float* cand_s = (float*)alloc((size_t)N_CAND * 4);
    int*   cand_i = (int*)  alloc((size_t)N_CAND * 4);
    int*   incl   = (int*)  alloc((size_t)N_NODES * 4);
    int*   bsum   = (int*)  alloc((size_t)N_CHUNKBLKS * 4);
    int*   boff   = (int*)  alloc((size_t)N_CHUNKBLKS * 4);

    int nblk = (N_NODES + 255) / 256;     // 196
    int eblk = (N_EDGES + 255) / 256;     // 2344
    int aggblk = (N_NODES / 4) * 8;       // 100000: nodegroups x 8 slices

    hipLaunchKernelGGL(k_init, dim3(nblk), dim3(256), 0, stream, packed, q);
    hipLaunchKernelGGL(k_deg, dim3(eblk), dim3(256), 0, stream, e_dst, ew, packed, rank);
    hipLaunchKernelGGL(k_scan_blk, dim3(nblk), dim3(256), 0, stream, packed, dinv, incl, bsum);
    hipLaunchKernelGGL(k_scan_top, dim3(1), dim3(256), 0, stream, bsum, boff);
    hipLaunchKernelGGL(k_scan_add, dim3(nblk), dim3(256), 0, stream, incl, boff, rowp);
    hipLaunchKernelGGL(k_fill, dim3(eblk), dim3(256), 0, stream, e_src, e_dst, ew, rank,
                       dinv, rowp, recs);
    hipLaunchKernelGGL(k_q, dim3(8), dim3(192), 0, stream, hs, Wattn, q);
    // conv1
    hipLaunchKernelGGL(k_gemm, dim3((N_NODES + GBM - 1) / GBM), dim3(256), 0, stream,
                       x, D_IN, x, 0, W1, bufA);
    hipLaunchKernelGGL(k_agg, dim3(aggblk), dim3(256), 0, stream,
                       bufA, dinv, rowp, recs, b1, bufB, 1);
    // conv2
    hipLaunchKernelGGL(k_gemm, dim3((N_NODES + GBM - 1) / GBM), dim3(256), 0, stream,
                       bufB, D_MID, attr, D_ATTR, W2, bufA);
    hipLaunchKernelGGL(k_agg, dim3(aggblk), dim3(256), 0, stream,
                       bufA, dinv, rowp, recs, b2, bufB, 0);
    // epilogue
    hipLaunchKernelGGL(k_post, dim3(CS_BLOCKS), dim3(256), 0, stream,
                       bufB, attr, q, partial, scores);
    hipLaunchKernelGGL(k_colsum_reduce, dim3(D_CAT / 4), dim3(256), 0, stream,
                       partial, colsum);
    hipLaunchKernelGGL(k_top1, dim3(N_CHUNKBLKS), dim3(256), 0, stream,
                       scores, cand_s, cand_i);
    hipLaunchKernelGGL(k_top2emb, dim3(1), dim3(256), 0, stream,
                       cand_s, cand_i, colsum, Wmap, bmap, bufB, attr, out);
}

// Round 13
// 284.364 us; speedup vs baseline: 1.5310x; 1.5310x over previous
//
#include <hip/hip_runtime.h>

#define N_NODES 50000
#define N_EDGES 600000
#define D_IN 128
#define D_MID 128
#define D_ATTR 32
#define D_OUT 128
#define D_EMB 256
#define D_H 768
#define K_TOP 16
#define D_CAT (D_OUT + D_ATTR)   // 160
#define N_CHUNKBLKS 196          // ceil(50000/256)
#define N_CAND (N_CHUNKBLKS * K_TOP)   // 3136
#define CSLOTS 13                // ceil(3136/256)
#define WSCALE 262144.0f         // 2^18 fixed-point for packed degree
#define CS_BLOCKS 768            // 768 = 3*256 exactly (reduce reads 3/thread)

// ---------------------------------------------------------------- init
__global__ void k_init(unsigned long long* packed, float* q) {
    int i = blockIdx.x * blockDim.x + threadIdx.x;
    if (i < N_NODES) packed[i] = 0ULL;
    if (i < D_CAT)   q[i] = 0.0f;
}

// ---------------------------------------------------------------- packed degree+count (+rank)
__global__ void k_deg(const int* __restrict__ dst, const float* __restrict__ w,
                      unsigned long long* __restrict__ packed, int* __restrict__ rank) {
    int e = blockIdx.x * blockDim.x + threadIdx.x;
    if (e < N_EDGES) {
        int d = dst[e];
        unsigned long long qv = (1ULL << 40)
                              + (unsigned long long)__float2uint_rn(w[e] * WSCALE);
        unsigned long long old = atomicAdd(&packed[d], qv);
        rank[e] = (int)(old >> 40);
    }
}

// ---------------------------------------------------------------- scan stage 1 (+ fused dinv)
__global__ __launch_bounds__(256) void k_scan_blk(const unsigned long long* __restrict__ packed,
                                                  float* __restrict__ dinv,
                                                  int* __restrict__ incl,
                                                  int* __restrict__ bsum) {
    __shared__ int sm[256];
    int tid = threadIdx.x;
    int i = blockIdx.x * 256 + tid;
    unsigned long long p = (i < N_NODES) ? packed[i] : 0ULL;
    int v = (int)(p >> 40);
    if (i < N_NODES) {
        float wsum = (float)(p & 0xFFFFFFFFFFULL) * (1.0f / WSCALE);
        dinv[i] = rsqrtf(1.0f + wsum);   // self-loop contributes 1
    }
    sm[tid] = v;
    __syncthreads();
    for (int off = 1; off < 256; off <<= 1) {
        int t = (tid >= off) ? sm[tid - off] : 0;
        __syncthreads();
        sm[tid] += t;
        __syncthreads();
    }
    if (i < N_NODES) incl[i] = sm[tid];
    if (tid == 255) bsum[blockIdx.x] = sm[255];
}

__global__ __launch_bounds__(256) void k_scan_top(const int* __restrict__ bsum,
                                                  int* __restrict__ boff) {
    __shared__ int sm[256];
    int tid = threadIdx.x;
    int v = (tid < N_CHUNKBLKS) ? bsum[tid] : 0;
    sm[tid] = v;
    __syncthreads();
    for (int off = 1; off < 256; off <<= 1) {
        int t = (tid >= off) ? sm[tid - off] : 0;
        __syncthreads();
        sm[tid] += t;
        __syncthreads();
    }
    if (tid < N_CHUNKBLKS) boff[tid] = sm[tid] - v;   // exclusive
}

__global__ __launch_bounds__(256) void k_scan_add(const int* __restrict__ incl,
                                                  const int* __restrict__ boff,
                                                  int* __restrict__ row_ptr) {
    int i = blockIdx.x * 256 + threadIdx.x;
    if (i < N_NODES) {
        row_ptr[i + 1] = incl[i] + boff[blockIdx.x];
        if (i == 0) row_ptr[0] = 0;
    }
}

// ---------------------------------------------------------------- CSR fill (no cursor atomic)
__global__ void k_fill(const int* __restrict__ src, const int* __restrict__ dst,
                       const float* __restrict__ w, const int* __restrict__ rank,
                       const float* __restrict__ dinv, const int* __restrict__ rowp,
                       int2* __restrict__ recs) {
    int e = blockIdx.x * blockDim.x + threadIdx.x;
    if (e < N_EDGES) {
        int s = src[e], d = dst[e];
        int pos = rowp[d] + rank[e];
        float nr = dinv[s] * w[e] * dinv[d];
        recs[pos] = make_int2(s, __float_as_int(nr));
    }
}

// ---------------------------------------------------------------- GEMM: out[N,128] = [in1|in2] @ W
// GBM=64 rows/block, 256 thr, 2 rows x 16 strided cols/thread. Conflict-free ws reads.
#define GBM 64
#define GBK 32
__global__ __launch_bounds__(256) void k_gemm(
    const float* __restrict__ in1, int d1,
    const float* __restrict__ in2, int d2,
    const float* __restrict__ W,      // [(d1+d2) x 128]
    float* __restrict__ out)          // [N x 128]
{
    __shared__ float xs[GBM][GBK + 1];   // 64x33
    __shared__ float ws[GBK][128];       // 32x128
    int tid = threadIdx.x;
    int cx = tid & 7;          // strided col groups: cx*4 + j4*32
    int ry = tid >> 3;         // rows ry*2, ry*2+1
    int row0 = blockIdx.x * GBM;
    float acc[2][16];
#pragma unroll
    for (int i = 0; i < 2; ++i)
#pragma unroll
        for (int j = 0; j < 16; ++j) acc[i][j] = 0.0f;
    int KD = d1 + d2;
    for (int kt = 0; kt < KD; kt += GBK) {
        const float* srcp; int sd, scol;
        if (kt < d1) { srcp = in1; sd = d1; scol = kt; }
        else         { srcp = in2; sd = d2; scol = kt - d1; }
#pragma unroll
        for (int i = 0; i < 2; ++i) {
            int vid = tid + i * 256;
            int rr = vid >> 3;
            int kc = (vid & 7) * 4;
            int r = row0 + rr;
            float4 val = make_float4(0.f, 0.f, 0.f, 0.f);
            if (r < N_NODES)
                val = *(const float4*)(srcp + (size_t)r * sd + scol + kc);
            xs[rr][kc + 0] = val.x;
            xs[rr][kc + 1] = val.y;
            xs[rr][kc + 2] = val.z;
            xs[rr][kc + 3] = val.w;
        }
#pragma unroll
        for (int i = 0; i < 4; ++i) {
            int vid = tid + i * 256;
            int kk = vid >> 5;
            int c = (vid & 31) * 4;
            *(float4*)&ws[kk][c] = *(const float4*)(W + (size_t)(kt + kk) * 128 + c);
        }
        __syncthreads();
#pragma unroll
        for (int kk = 0; kk < GBK; ++kk) {
            float xv0 = xs[ry * 2 + 0][kk];
            float xv1 = xs[ry * 2 + 1][kk];
            float wv[16];
#pragma unroll
            for (int j4 = 0; j4 < 4; ++j4)
                *(float4*)&wv[j4 * 4] = *(float4*)&ws[kk][cx * 4 + j4 * 32];
#pragma unroll
            for (int j = 0; j < 16; ++j) {
                acc[0][j] += xv0 * wv[j];
                acc[1][j] += xv1 * wv[j];
            }
        }
        __syncthreads();
    }
#pragma unroll
    for (int i = 0; i < 2; ++i) {
        int r = row0 + ry * 2 + i;
        if (r < N_NODES) {
#pragma unroll
            for (int j4 = 0; j4 < 4; ++j4)
                *(float4*)(out + (size_t)r * 128 + cx * 4 + j4 * 32)
                    = *(float4*)&acc[i][j4 * 4];
        }
    }
}

// ---------------------------------------------------------------- aggregation (CSR gather)
// One 64-lane wave per node, float2 per lane (512B/row coalesced); recs pre-loaded
// coalesced, shfl broadcast; gathers batched 8-deep. ~3.57 TB/s TCC = fabric floor
// for this random-512B pattern (r12's column-slicing attempt made it 2.5x worse).
__global__ __launch_bounds__(256) void k_agg(
    const float* __restrict__ t, const float* __restrict__ dinv,
    const int* __restrict__ row_ptr, const int2* __restrict__ recs,
    const float* __restrict__ bias,
    float* __restrict__ out, int relu_flag)
{
    int lane = threadIdx.x & 63;
    int node = blockIdx.x * 4 + (threadIdx.x >> 6);
    if (node >= N_NODES) return;
    const float2* t2 = (const float2*)t;
    float di = dinv[node];
    float sw = di * di;
    float2 v = t2[(size_t)node * 64 + lane];
    float accx = v.x * sw, accy = v.y * sw;
    int e0 = row_ptr[node], e1 = row_ptr[node + 1];
    int len = e1 - e0;
    for (int base = 0; base < len; base += 64) {
        int m = len - base; if (m > 64) m = 64;
        int2 myrec = make_int2(0, 0);
        if (lane < m) myrec = recs[e0 + base + lane];
        int j = 0;
        for (; j + 8 <= m; j += 8) {
            int   s0 = __shfl(myrec.x, j + 0, 64), s1 = __shfl(myrec.x, j + 1, 64);
            int   s2 = __shfl(myrec.x, j + 2, 64), s3 = __shfl(myrec.x, j + 3, 64);
            int   s4 = __shfl(myrec.x, j + 4, 64), s5 = __shfl(myrec.x, j + 5, 64);
            int   s6 = __shfl(myrec.x, j + 6, 64), s7 = __shfl(myrec.x, j + 7, 64);
            float w0 = __int_as_float(__shfl(myrec.y, j + 0, 64));
            float w1 = __int_as_float(__shfl(myrec.y, j + 1, 64));
            float w2 = __int_as_float(__shfl(myrec.y, j + 2, 64));
            float w3 = __int_as_float(__shfl(myrec.y, j + 3, 64));
            float w4 = __int_as_float(__shfl(myrec.y, j + 4, 64));
            float w5 = __int_as_float(__shfl(myrec.y, j + 5, 64));
            float w6 = __int_as_float(__shfl(myrec.y, j + 6, 64));
            float w7 = __int_as_float(__shfl(myrec.y, j + 7, 64));
            float2 u0 = t2[(size_t)s0 * 64 + lane];
            float2 u1 = t2[(size_t)s1 * 64 + lane];
            float2 u2 = t2[(size_t)s2 * 64 + lane];
            float2 u3 = t2[(size_t)s3 * 64 + lane];
            float2 u4 = t2[(size_t)s4 * 64 + lane];
            float2 u5 = t2[(size_t)s5 * 64 + lane];
            float2 u6 = t2[(size_t)s6 * 64 + lane];
            float2 u7 = t2[(size_t)s7 * 64 + lane];
            accx += w0 * u0.x + w1 * u1.x + w2 * u2.x + w3 * u3.x
                  + w4 * u4.x + w5 * u5.x + w6 * u6.x + w7 * u7.x;
            accy += w0 * u0.y + w1 * u1.y + w2 * u2.y + w3 * u3.y
                  + w4 * u4.y + w5 * u5.y + w6 * u6.y + w7 * u7.y;
        }
        for (; j + 4 <= m; j += 4) {
            int s0 = __shfl(myrec.x, j + 0, 64);
            int s1 = __shfl(myrec.x, j + 1, 64);
            int s2 = __shfl(myrec.x, j + 2, 64);
            int s3 = __shfl(myrec.x, j + 3, 64);
            float w0 = __int_as_float(__shfl(myrec.y, j + 0, 64));
            float w1 = __int_as_float(__shfl(myrec.y, j + 1, 64));
            float w2 = __int_as_float(__shfl(myrec.y, j + 2, 64));
            float w3 = __int_as_float(__shfl(myrec.y, j + 3, 64));
            float2 u0 = t2[(size_t)s0 * 64 + lane];
            float2 u1 = t2[(size_t)s1 * 64 + lane];
            float2 u2 = t2[(size_t)s2 * 64 + lane];
            float2 u3 = t2[(size_t)s3 * 64 + lane];
            accx += w0 * u0.x + w1 * u1.x + w2 * u2.x + w3 * u3.x;
            accy += w0 * u0.y + w1 * u1.y + w2 * u2.y + w3 * u3.y;
        }
        for (; j < m; ++j) {
            int s = __shfl(myrec.x, j, 64);
            float wn = __int_as_float(__shfl(myrec.y, j, 64));
            float2 u = t2[(size_t)s * 64 + lane];
            accx += wn * u.x;
            accy += wn * u.y;
        }
    }
    const float2* b2 = (const float2*)bias;
    float2 bb = b2[lane];
    accx += bb.x; accy += bb.y;
    if (relu_flag) {
        accx = fmaxf(accx, 0.0f);
        accy = fmaxf(accy, 0.0f);
    }
    float2 res; res.x = accx; res.y = accy;
    ((float2*)out)[(size_t)node * 64 + lane] = res;
}

// ---------------------------------------------------------------- q = hidden_state @ Wattn  [160]
__global__ void k_q(const float* __restrict__ hs, const float* __restrict__ Wattn,
                    float* __restrict__ q) {
    int j = threadIdx.x;
    if (j >= D_CAT) return;
    int k0 = blockIdx.x * (D_H / 8);       // grid 8
    float acc = 0.0f;
    for (int k = k0; k < k0 + D_H / 8; k++) acc += hs[k] * Wattn[k * D_CAT + j];
    atomicAdd(&q[j], acc);
}

// ---------------------------------------------------------------- post: colsum partials + scores
// One streaming pass over h2+attr. Phase1: 32-lane groups own a row -> colsum float4
// accum + score dot (width-32 shfl reduce, stashed in LDS). Phase2: attr, width-8.
__global__ __launch_bounds__(256) void k_post(const float* __restrict__ h2,
                                              const float* __restrict__ attr,
                                              const float* __restrict__ q,
                                              float* __restrict__ partial,
                                              float* __restrict__ scores) {
    __shared__ float4 sm[256];
    __shared__ float rowsc[80];
    int tid = threadIdx.x;
    int per = (N_NODES + CS_BLOCKS - 1) / CS_BLOCKS;   // 66
    int r0 = blockIdx.x * per;
    int r1 = min(N_NODES, r0 + per);
    float* myrow = partial + (size_t)blockIdx.x * D_CAT;
    {
        const float4* h4 = (const float4*)h2;          // row stride 32 float4
        int c = tid & 31;
        float4 qv = ((const float4*)q)[c];
        float4 acc = make_float4(0.f, 0.f, 0.f, 0.f);
        for (int r = r0 + (tid >> 5); r < r1; r += 8) {
            float4 v = h4[(size_t)r * 32 + c];
            acc.x += v.x; acc.y += v.y; acc.z += v.z; acc.w += v.w;
            float sd = v.x * qv.x + v.y * qv.y + v.z * qv.z + v.w * qv.w;
#pragma unroll
            for (int off = 16; off; off >>= 1) sd += __shfl_xor(sd, off, 32);
            if (c == 0) rowsc[r - r0] = sd;
        }
        sm[tid] = acc;
        __syncthreads();
        if (tid < 32) {
            float4 s = sm[tid];
#pragma unroll
            for (int g = 1; g < 8; ++g) {
                float4 v = sm[g * 32 + tid];
                s.x += v.x; s.y += v.y; s.z += v.z; s.w += v.w;
            }
            ((float4*)myrow)[tid] = s;
        }
        __syncthreads();
    }
    {
        const float4* a4 = (const float4*)attr;        // row stride 8 float4
        int c = tid & 7;
        float4 qv = ((const float4*)q)[32 + c];
        float4 acc = make_float4(0.f, 0.f, 0.f, 0.f);
        for (int r = r0 + (tid >> 3); r < r1; r += 32) {
            float4 v = a4[(size_t)r * 8 + c];
            acc.x += v.x; acc.y += v.y; acc.z += v.z; acc.w += v.w;
            float sd = v.x * qv.x + v.y * qv.y + v.z * qv.z + v.w * qv.w;
#pragma unroll
            for (int off = 4; off; off >>= 1) sd += __shfl_xor(sd, off, 8);
            if (c == 0) scores[r] = rowsc[r - r0] + sd;
        }
        sm[tid] = acc;
        __syncthreads();
        if (tid < 8) {
            float4 s = sm[tid];
#pragma unroll
            for (int g = 1; g < 32; ++g) {
                float4 v = sm[g * 8 + tid];
                s.x += v.x; s.y += v.y; s.z += v.z; s.w += v.w;
            }
            ((float4*)(myrow + D_OUT))[tid] = s;
        }
    }
}

// ---------------------------------------------------------------- column sums, stage B
__global__ __launch_bounds__(256) void k_colsum_reduce(const float* __restrict__ partial,
                                                       float* __restrict__ colsum) {
    __shared__ float4 sm[256];
    int tid = threadIdx.x;
    int cg = blockIdx.x;
    float4 acc = make_float4(0.f, 0.f, 0.f, 0.f);
#pragma unroll
    for (int k = 0; k < 3; ++k) {
        int b = tid + k * 256;
        float4 v = *(const float4*)(partial + (size_t)b * D_CAT + cg * 4);
        acc.x += v.x; acc.y += v.y; acc.z += v.z; acc.w += v.w;
    }
    sm[tid] = acc;
    __syncthreads();
    for (int off = 128; off; off >>= 1) {
        if (tid < off) {
            float4 v = sm[tid + off];
            sm[tid].x += v.x; sm[tid].y += v.y; sm[tid].z += v.z; sm[tid].w += v.w;
        }
        __syncthreads();
    }
    if (tid == 0) *(float4*)(colsum + cg * 4) = sm[0];
}

// ---------------------------------------------------------------- top-k stage 1 (wave-shuffle)
__global__ __launch_bounds__(256) void k_top1(const float* __restrict__ scores,
                                              float* __restrict__ cand_s,
                                              int* __restrict__ cand_i) {
    int tid = threadIdx.x;
    int lane = tid & 63;
    int wave = tid >> 6;
    int i = blockIdx.x * 256 + tid;
    float s = (i < N_NODES) ? scores[i] : -INFINITY;
    int ix = i;
    __shared__ float wls[4];
    __shared__ int   wli[4];
    __shared__ int   fin_i;
    for (int it = 0; it < K_TOP; ++it) {
        float bs = s; int bi = ix;
#pragma unroll
        for (int off = 32; off; off >>= 1) {
            float s2 = __shfl_xor(bs, off, 64);
            int   i2 = __shfl_xor(bi, off, 64);
            if (s2 > bs || (s2 == bs && i2 < bi)) { bs = s2; bi = i2; }
        }
        if (lane == 0) { wls[wave] = bs; wli[wave] = bi; }
        __syncthreads();
        if (tid == 0) {
            float f = wls[0]; int fi = wli[0];
#pragma unroll
            for (int w = 1; w < 4; ++w)
                if (wls[w] > f || (wls[w] == f && wli[w] < fi)) { f = wls[w]; fi = wli[w]; }
            cand_s[blockIdx.x * K_TOP + it] = f;
            cand_i[blockIdx.x * K_TOP + it] = fi;
            fin_i = fi;
        }
        __syncthreads();
        if (ix == fin_i) s = -INFINITY;
    }
}

// ---------------------------------------------------------------- top-k stage 2 + emb + gather
__global__ __launch_bounds__(256) void k_top2emb(
    const float* __restrict__ cand_s, const int* __restrict__ cand_i,
    const float* __restrict__ colsum, const float* __restrict__ Wmap,
    const float* __restrict__ bmap,
    const float* __restrict__ h2, const float* __restrict__ attr,
    float* __restrict__ out)
{
    float s[CSLOTS]; int ix[CSLOTS];
    int tid = threadIdx.x;
    int lane = tid & 63;
    int wave = tid >> 6;
#pragma unroll
    for (int j = 0; j < CSLOTS; ++j) {
        int c = tid + j * 256;
        s[j]  = (c < N_CAND) ? cand_s[c] : -INFINITY;
        ix[j] = (c < N_CAND) ? cand_i[c] : 0x7fffffff;
    }
    __shared__ float wsum_s[4];
    __shared__ int   wsum_i[4];
    __shared__ int   win_i;
    __shared__ int   ti[K_TOP];
    for (int it = 0; it < K_TOP; ++it) {
        float bs = -INFINITY; int bi = 0x7fffffff;
#pragma unroll
        for (int j = 0; j < CSLOTS; ++j) {
            if (s[j] > bs || (s[j] == bs && ix[j] < bi)) { bs = s[j]; bi = ix[j]; }
        }
#pragma unroll
        for (int off = 32; off; off >>= 1) {
            float s2 = __shfl_xor(bs, off, 64);
            int   i2 = __shfl_xor(bi, off, 64);
            if (s2 > bs || (s2 == bs && i2 < bi)) { bs = s2; bi = i2; }
        }
        if (lane == 0) { wsum_s[wave] = bs; wsum_i[wave] = bi; }
        __syncthreads();
        if (tid == 0) {
            float ws0 = wsum_s[0]; int wi0 = wsum_i[0];
#pragma unroll
            for (int w = 1; w < 4; ++w) {
                float s2 = wsum_s[w]; int i2 = wsum_i[w];
                if (s2 > ws0 || (s2 == ws0 && i2 < wi0)) { ws0 = s2; wi0 = i2; }
            }
            win_i = wi0;
            ti[it] = wi0;
        }
        __syncthreads();
        int w = win_i;
#pragma unroll
        for (int j = 0; j < CSLOTS; ++j)
            if (ix[j] == w) s[j] = -INFINITY;
        __syncthreads();
    }
    __shared__ float cs[D_CAT];
    if (tid < D_CAT) cs[tid] = colsum[tid];
    __syncthreads();
    float acc = 0.0f;
#pragma unroll 8
    for (int k = 0; k < D_CAT; ++k) acc += cs[k] * Wmap[k * D_EMB + tid];
    out[tid] = acc * (1.0f / N_NODES) + bmap[tid];
    for (int idx = tid; idx < K_TOP * D_CAT; idx += 256) {
        int kk = idx / D_CAT;
        int d = idx % D_CAT;
        int node = ti[kk];
        out[D_EMB + idx] = (d < D_OUT) ? h2[node * D_OUT + d]
                                       : attr[node * D_ATTR + (d - D_OUT)];
    }
}

// ================================================================ host
extern "C" void kernel_launch(void* const* d_in, const int* in_sizes, int n_in,
                              void* d_out, int out_size, void* d_ws, size_t ws_size,
                              hipStream_t stream) {
    const float* x      = (const float*)d_in[0];
    const float* attr   = (const float*)d_in[1];
    const float* ew     = (const float*)d_in[2];
    const float* hs     = (const float*)d_in[3];
    const int*   ei     = (const int*)d_in[4];
    const float* W1     = (const float*)d_in[5];
    const float* b1     = (const float*)d_in[6];
    const float* W2     = (const float*)d_in[7];
    const float* b2     = (const float*)d_in[8];
    const float* Wmap   = (const float*)d_in[9];
    const float* bmap   = (const float*)d_in[10];
    const float* Wattn  = (const float*)d_in[11];
    float* out = (float*)d_out;
    const int* e_src = ei;
    const int* e_dst = ei + N_EDGES;

    size_t off = 0;
    auto alloc = [&](size_t bytes) {
        void* p = (char*)d_ws + off;
        off += (bytes + 255) / 256 * 256;
        return p;
    };
    unsigned long long* packed = (unsigned long long*)alloc((size_t)N_NODES * 8);
    float* dinv   = (float*)alloc((size_t)N_NODES * 4);
    int*   rowp   = (int*)  alloc((size_t)(N_NODES + 1) * 4);
    int*   rank   = (int*)  alloc((size_t)N_EDGES * 4);
    int2*  recs   = (int2*) alloc((size_t)N_EDGES * 8);
    float* bufA   = (float*)alloc((size_t)N_NODES * 128 * 4);
    float* bufB   = (float*)alloc((size_t)N_NODES * 128 * 4);
    float* scores = (float*)alloc((size_t)N_NODES * 4);
    float* q      = (float*)alloc(D_CAT * 4);
    float* colsum = (float*)alloc(D_CAT * 4);
    float* partial= (float*)alloc((size_t)CS_BLOCKS * D_CAT * 4);
    float* cand_s = (float*)alloc((size_t)N_CAND * 4);
    int*   cand_i = (int*)  alloc((size_t)N_CAND * 4);
    int*   incl   = (int*)  alloc((size_t)N_NODES * 4);
    int*   bsum   = (int*)  alloc((size_t)N_CHUNKBLKS * 4);
    int*   boff   = (int*)  alloc((size_t)N_CHUNKBLKS * 4);

    int nblk = (N_NODES + 255) / 256;     // 196
    int eblk = (N_EDGES + 255) / 256;     // 2344

    hipLaunchKernelGGL(k_init, dim3(nblk), dim3(256), 0, stream, packed, q);
    hipLaunchKernelGGL(k_deg, dim3(eblk), dim3(256), 0, stream, e_dst, ew, packed, rank);
    hipLaunchKernelGGL(k_scan_blk, dim3(nblk), dim3(256), 0, stream, packed, dinv, incl, bsum);
    hipLaunchKernelGGL(k_scan_top, dim3(1), dim3(256), 0, stream, bsum, boff);
    hipLaunchKernelGGL(k_scan_add, dim3(nblk), dim3(256), 0, stream, incl, boff, rowp);
    hipLaunchKernelGGL(k_fill, dim3(eblk), dim3(256), 0, stream, e_src, e_dst, ew, rank,
                       dinv, rowp, recs);
    hipLaunchKernelGGL(k_q, dim3(8), dim3(192), 0, stream, hs, Wattn, q);
    // conv1
    hipLaunchKernelGGL(k_gemm, dim3((N_NODES + GBM - 1) / GBM), dim3(256), 0, stream,
                       x, D_IN, x, 0, W1, bufA);
    hipLaunchKernelGGL(k_agg, dim3((N_NODES + 3) / 4), dim3(256), 0, stream,
                       bufA, dinv, rowp, recs, b1, bufB, 1);
    // conv2
    hipLaunchKernelGGL(k_gemm, dim3((N_NODES + GBM - 1) / GBM), dim3(256), 0, stream,
                       bufB, D_MID, attr, D_ATTR, W2, bufA);
    hipLaunchKernelGGL(k_agg, dim3((N_NODES + 3) / 4), dim3(256), 0, stream,
                       bufA, dinv, rowp, recs, b2, bufB, 0);
    // epilogue
    hipLaunchKernelGGL(k_post, dim3(CS_BLOCKS), dim3(256), 0, stream,
                       bufB, attr, q, partial, scores);
    hipLaunchKernelGGL(k_colsum_reduce, dim3(D_CAT / 4), dim3(256), 0, stream,
                       partial, colsum);
    hipLaunchKernelGGL(k_top1, dim3(N_CHUNKBLKS), dim3(256), 0, stream,
                       scores, cand_s, cand_i);
    hipLaunchKernelGGL(k_top2emb, dim3(1), dim3(256), 0, stream,
                       cand_s, cand_i, colsum, Wmap, bmap, bufB, attr, out);
}